// Round 4
// baseline (182.012 us; speedup 1.0000x reference)
//
#include <hip/hip_runtime.h>
#include <hip/hip_bf16.h>
#include <cstdint>

// Problem dims (fixed by the reference):
//   x: [8, 8192, 512] f32 -> LN over E=512 -> view as A=[16384, 2048]
//   (reshape is row-major flatten: A[m][k] = LN(x_flat)[m*2048+k])
//   W: [2048, 512] f32, b: [512];  out: [16384, 512] f32 = gelu(A @ W' + b')
//   where W' = gamma-folded W, b' = b + beta @ W  (LN affine folded out)
#define XROWS   65536
#define E       512
#define MROWS   16384
#define KDIM    2048
#define NDIM    512
#define NT      32        // K-steps of 64

typedef __attribute__((ext_vector_type(4))) float f32x4;
typedef __attribute__((ext_vector_type(2))) float f32x2;
typedef __attribute__((ext_vector_type(8))) unsigned short u16x8;
typedef __attribute__((ext_vector_type(8))) __bf16 bf16x8;

__device__ __forceinline__ unsigned short f2bf(float f) {
  unsigned u = __builtin_bit_cast(unsigned, f);
  u += 0x7FFFu + ((u >> 16) & 1u);   // round-to-nearest-even
  return (unsigned short)(u >> 16);
}

// fast exact-enough gelu: tanh form via native exp2/rcp.
// gelu ~= v*E/(E+1), E = 2^(v*(c1 + c3*v^2));  |err vs erf-form| <= ~3e-3
__device__ __forceinline__ float gelu_f(float v) {
  float p = v * (2.3022083f + 0.1029432f * (v * v));
  p = fminf(p, 80.0f);                       // overflow guard (E=inf -> NaN)
  const float Ee = exp2f(p);                 // native v_exp_f32
  return v * Ee * __builtin_amdgcn_rcpf(Ee + 1.0f);
}

// ---------------------------------------------------------------------------
// W [2048][512] f32 -> WT [512][2048] bf16 with gamma folded in:
//   WT[n][k] = bf16(gamma[k % 512] * W[k][n])
// ---------------------------------------------------------------------------
__global__ __launch_bounds__(256) void wt_kernel(const float* __restrict__ W,
                                                 const float* __restrict__ gamma,
                                                 unsigned short* __restrict__ WT) {
  __shared__ float tile[64][68];
  const int t  = threadIdx.x;
  const int bk = blockIdx.x >> 3;
  const int bn = blockIdx.x & 7;
  const int c4 = (t & 15) * 4;
#pragma unroll
  for (int i = 0; i < 4; ++i) {
    const int r = (t >> 4) + i * 16;
    const f32x4 v = *(const f32x4*)&W[(size_t)(bk * 64 + r) * NDIM + bn * 64 + c4];
    tile[r][c4 + 0] = v.x; tile[r][c4 + 1] = v.y;
    tile[r][c4 + 2] = v.z; tile[r][c4 + 3] = v.w;
  }
  __syncthreads();
#pragma unroll
  for (int j = 0; j < 2; ++j) {
    const int n  = j * 32 + (t >> 3);
    const int kb = (t & 7) * 8;
    const int kg0 = (bk & 7) * 64 + kb;      // gamma idx = global k & 511
    const f32x4 g0 = *(const f32x4*)(gamma + kg0);
    const f32x4 g1 = *(const f32x4*)(gamma + kg0 + 4);
    const float gg[8] = {g0.x, g0.y, g0.z, g0.w, g1.x, g1.y, g1.z, g1.w};
    u16x8 o;
#pragma unroll
    for (int q = 0; q < 8; ++q) o[q] = f2bf(gg[q] * tile[kb + q][n]);
    *(u16x8*)&WT[(size_t)(bn * 64 + n) * KDIM + bk * 64 + kb] = o;
  }
}

// ---------------------------------------------------------------------------
// beta fold, deterministic 2-stage: partial[32][512] then reduce + b.
// ---------------------------------------------------------------------------
__global__ __launch_bounds__(256) void kbias1(const float* __restrict__ W,
                                              const float* __restrict__ beta,
                                              float* __restrict__ partial) {
  const int bk = blockIdx.x, tid = threadIdx.x;
  float a0 = 0.f, a1 = 0.f;
  for (int k = 0; k < 64; ++k) {
    const int kg = bk * 64 + k;
    const float be = beta[kg & (E - 1)];
    a0 += be * W[(size_t)kg * NDIM + tid];
    a1 += be * W[(size_t)kg * NDIM + 256 + tid];
  }
  partial[bk * NDIM + tid] = a0;
  partial[bk * NDIM + 256 + tid] = a1;
}

__global__ __launch_bounds__(256) void kbias2(const float* __restrict__ b,
                                              const float* __restrict__ partial,
                                              float* __restrict__ biasf) {
  const int c = blockIdx.x * 256 + threadIdx.x;   // grid 2 x 256
  float s = b[c];
  for (int j = 0; j < 32; ++j) s += partial[j * NDIM + c];
  biasf[c] = s;
}

// ---------------------------------------------------------------------------
// Stats: one wave per x-row of 512 -> (rs, nm) = (rstd, -mean*rstd)
// ---------------------------------------------------------------------------
__global__ __launch_bounds__(256, 4) void stats_kernel(const float* __restrict__ x,
                                                       f32x2* __restrict__ stats) {
  const int w = threadIdx.x >> 6, l = threadIdx.x & 63;
  const size_t row = (size_t)blockIdx.x * 4 + w;
  const float* xr = x + row * E + l * 8;
  const f32x4 v0 = *(const f32x4*)xr;
  const f32x4 v1 = *(const f32x4*)(xr + 4);
  float s = v0.x + v0.y + v0.z + v0.w + v1.x + v1.y + v1.z + v1.w;
  float q = v0.x * v0.x + v0.y * v0.y + v0.z * v0.z + v0.w * v0.w
          + v1.x * v1.x + v1.y * v1.y + v1.z * v1.z + v1.w * v1.w;
#pragma unroll
  for (int off = 32; off > 0; off >>= 1) {
    s += __shfl_xor(s, off);
    q += __shfl_xor(q, off);
  }
  if (l == 0) {
    const float mean = s * (1.0f / E);
    const float var  = q * (1.0f / E) - mean * mean;
    const float rs   = rsqrtf(var + 1e-6f);
    f32x2 o; o.x = rs; o.y = -mean * rs;
    stats[row] = o;
  }
}

// ---------------------------------------------------------------------------
// Fused norm+GEMM, B-direct-from-L2 variant.
// Tile 64x128, 4 waves 2x2 (wave = 32x64 output). A: x f32 -> reg (2-deep
// dbuf) -> LN fma -> bf16 -> swizzled ds_write; LDS = 2 x 8KB (A only).
// B: WT is 2MB, L2-resident -> fragments loaded global->VGPR one step early.
// grid = 256 bm x 4 bn (bn in low bits: siblings share x-panel via L3).
// ---------------------------------------------------------------------------
__global__ __launch_bounds__(256, 3) void gemm_kernel(const float* __restrict__ x,
                                                      const f32x2* __restrict__ stats,
                                                      const unsigned short* __restrict__ Bt,
                                                      const float* __restrict__ biasf,
                                                      float* __restrict__ out) {
  __shared__ char smem[2 * 8192];   // dbuf A: 64 rows x 128B (bf16, swizzled)
  const int tid = threadIdx.x;
  const int l = tid & 63, w = tid >> 6;
  const int l7 = l & 7, l15 = l & 15, lhi = l >> 4;
  const int wr = w >> 1, wc = w & 1;

  const int bn = blockIdx.x & 3;
  const int bm = blockIdx.x >> 2;
  const size_t mrow0 = (size_t)bm * 64;
  const int    ncol0 = bn * 128;

  // A staging: thread covers rows {amrow, amrow+32}, f32 cols (tid&7)*8..+8
  const int amrow = tid >> 3;
  const int acol  = (tid & 7) * 8;
  const float* gx = x + (mrow0 + amrow) * KDIM + acol;
  const int sbase = (int)(mrow0 + amrow) * 4;            // stats idx base
  const int awz   = ((tid & 7) * 16) ^ ((amrow & 7) << 4);

  // B fragment base: WT[col][k], col = ncol0 + wc*64 + n*16 + l15
  const unsigned short* gBf = Bt + (size_t)(ncol0 + wc * 64 + l15) * KDIM + lhi * 8;

  f32x4 acc[2][4];
#pragma unroll
  for (int m = 0; m < 2; ++m)
#pragma unroll
    for (int n = 0; n < 4; ++n) acc[m][n] = (f32x4){0.f, 0.f, 0.f, 0.f};

  // A-frag swizzled byte col: ((kk*64) ^ (lhi*16)) ^ ((row&7)<<4), row&7 == l7
  const int cs0 = (lhi * 16) ^ (l7 * 16);

  f32x4 xa0[4], xa1[4];
  f32x2 st0[2], st1[2];
  bf16x8 bvr[8];   // B frags for one K-step: [kk][n], fully unrolled indices

  auto loadx = [&](f32x4* XA, f32x2* ST, int t) {
    const float* p = gx + (size_t)t * 64;
    XA[0] = *(const f32x4*)(p);
    XA[1] = *(const f32x4*)(p + 4);
    XA[2] = *(const f32x4*)(p + (size_t)32 * KDIM);
    XA[3] = *(const f32x4*)(p + (size_t)32 * KDIM + 4);
    ST[0] = stats[sbase + (t >> 3)];
    ST[1] = stats[sbase + 128 + (t >> 3)];
  };
  auto writeA = [&](const f32x4* XA, const f32x2* ST, int t) {
    char* ab = smem + (t & 1) * 8192;
    u16x8 o;
    float rs = ST[0].x, nm = ST[0].y;
    o[0] = f2bf(XA[0].x * rs + nm); o[1] = f2bf(XA[0].y * rs + nm);
    o[2] = f2bf(XA[0].z * rs + nm); o[3] = f2bf(XA[0].w * rs + nm);
    o[4] = f2bf(XA[1].x * rs + nm); o[5] = f2bf(XA[1].y * rs + nm);
    o[6] = f2bf(XA[1].z * rs + nm); o[7] = f2bf(XA[1].w * rs + nm);
    *(u16x8*)(ab + amrow * 128 + awz) = o;
    rs = ST[1].x; nm = ST[1].y;
    o[0] = f2bf(XA[2].x * rs + nm); o[1] = f2bf(XA[2].y * rs + nm);
    o[2] = f2bf(XA[2].z * rs + nm); o[3] = f2bf(XA[2].w * rs + nm);
    o[4] = f2bf(XA[3].x * rs + nm); o[5] = f2bf(XA[3].y * rs + nm);
    o[6] = f2bf(XA[3].z * rs + nm); o[7] = f2bf(XA[3].w * rs + nm);
    *(u16x8*)(ab + (amrow + 32) * 128 + awz) = o;
  };
  auto loadB = [&](int t) {
    const unsigned short* p = gBf + (size_t)t * 64;
#pragma unroll
    for (int kk = 0; kk < 2; ++kk)
#pragma unroll
      for (int n = 0; n < 4; ++n)
        bvr[kk * 4 + n] = *(const bf16x8*)(p + (size_t)n * 16 * KDIM + kk * 32);
  };
  auto mm = [&](int t) {
    const char* Ab = smem + (t & 1) * 8192;
#pragma unroll
    for (int kk = 0; kk < 2; ++kk) {
      const int co = cs0 ^ (kk * 64);
      bf16x8 av[2];
#pragma unroll
      for (int m = 0; m < 2; ++m)
        av[m] = *(const bf16x8*)(Ab + (wr * 32 + m * 16 + l15) * 128 + co);
#pragma unroll
      for (int m = 0; m < 2; ++m)
#pragma unroll
        for (int n = 0; n < 4; ++n)
          acc[m][n] = __builtin_amdgcn_mfma_f32_16x16x32_bf16(av[m], bvr[kk * 4 + n],
                                                              acc[m][n], 0, 0, 0);
    }
  };

  // prologue: stage t=0 (A in LDS, B in regs); prefetch x for t=1
  loadx(xa0, st0, 0);
  writeA(xa0, st0, 0);
  loadB(0);
  loadx(xa1, st1, 1);
  __syncthreads();

  for (int t = 0; t < NT; t += 2) {
    // even step: compute buf0; B(t+1)->regs; A(t+1)->buf1; x(t+2)->xa0
    if (t + 2 < NT) loadx(xa0, st0, t + 2);
    mm(t);
    if (t + 1 < NT) { loadB(t + 1); writeA(xa1, st1, t + 1); }
    __syncthreads();
    // odd step: compute buf1; B(t+2)->regs; A(t+2)->buf0; x(t+3)->xa1
    if (t + 3 < NT) loadx(xa1, st1, t + 3);
    mm(t + 1);
    if (t + 2 < NT) { loadB(t + 2); writeA(xa0, st0, t + 2); }
    __syncthreads();
  }

  // epilogue: bias + fast gelu, f32 store
  // C/D layout (verified m89): col = l&15, row = (l>>4)*4 + reg
#pragma unroll
  for (int n = 0; n < 4; ++n) {
    const int col = ncol0 + wc * 64 + n * 16 + l15;
    const float bb = biasf[col];
#pragma unroll
    for (int m = 0; m < 2; ++m) {
      const size_t rbase = mrow0 + wr * 32 + m * 16 + lhi * 4;
#pragma unroll
      for (int r = 0; r < 4; ++r) {
        const float v = acc[m][n][r] + bb;
        out[(rbase + r) * NDIM + col] = gelu_f(v);
      }
    }
  }
}

// ---------------------------------------------------------------------------
extern "C" void kernel_launch(void* const* d_in, const int* in_sizes, int n_in,
                              void* d_out, int out_size, void* d_ws, size_t ws_size,
                              hipStream_t stream) {
  const float* x     = (const float*)d_in[0];
  const float* gamma = (const float*)d_in[1];
  const float* beta  = (const float*)d_in[2];
  const float* W     = (const float*)d_in[3];
  const float* b     = (const float*)d_in[4];
  float* out = (float*)d_out;

  // ws layout: WT 2MB | stats 512KB | partial 64KB | biasf 2KB
  char* p = (char*)d_ws;
  unsigned short* WT = (unsigned short*)p;            p += (size_t)NDIM * KDIM * 2;
  f32x2* stats       = (f32x2*)p;                     p += (size_t)XROWS * 8;
  float* partial     = (float*)p;                     p += (size_t)32 * NDIM * 4;
  float* biasf       = (float*)p;

  wt_kernel<<<256, 256, 0, stream>>>(W, gamma, WT);
  kbias1<<<32, 256, 0, stream>>>(W, beta, partial);
  kbias2<<<2, 256, 0, stream>>>(b, partial, biasf);
  stats_kernel<<<XROWS / 4, 256, 0, stream>>>(x, stats);
  gemm_kernel<<<(MROWS / 64) * 4, 256, 0, stream>>>(x, stats, WT, biasf, out);
}

// Round 6
// 97.822 us; speedup vs baseline: 1.8606x; 1.8606x over previous
//
#include <hip/hip_runtime.h>
#include <hip/hip_bf16.h>
#include <cstdint>

// x: [8,8192,512] f32 -> LN over E=512 -> A=[16384,2048] (row-major flatten)
// W: [2048,512] f32, b: [512]; out = gelu(A @ W' + b'),
// W' = gamma-folded W (bf16, transposed), b' = b + beta @ W.
#define XROWS   65536
#define E       512
#define MROWS   16384
#define KDIM    2048
#define NDIM    512
#define NT      32        // K-steps of 64

typedef __attribute__((ext_vector_type(4))) float f32x4;
typedef __attribute__((ext_vector_type(2))) float f32x2;
typedef __attribute__((ext_vector_type(8))) unsigned short u16x8;
typedef __attribute__((ext_vector_type(8))) __bf16 bf16x8;

__device__ __forceinline__ unsigned short f2bf(float f) {
  unsigned u = __builtin_bit_cast(unsigned, f);
  u += 0x7FFFu + ((u >> 16) & 1u);
  return (unsigned short)(u >> 16);
}

typedef const __attribute__((address_space(1))) unsigned char ga_u8;
typedef __attribute__((address_space(3))) unsigned char ls_u8;
__device__ __forceinline__ void gload16(const void* g, void* l) {
  __builtin_amdgcn_global_load_lds((ga_u8*)g, (ls_u8*)l, 16, 0, 0);
}

// fast gelu (tanh form), |err vs erf form| <= ~3e-3 << 0.094 threshold
__device__ __forceinline__ float gelu_f(float v) {
  float p = v * (2.3022083f + 0.1029432f * (v * v));
  p = fminf(p, 80.0f);
  const float Ee = exp2f(p);
  return v * Ee * __builtin_amdgcn_rcpf(Ee + 1.0f);
}

// sched fence: everything EXCEPT VMEM may cross (pins global-load issue order
// so the vmcnt FIFO composition below is provable).
// masks: ALU 1|VALU 2|SALU 4|MFMA 8|DS 0x80|DS_READ 0x100|DS_WRITE 0x200
#define SB_NOVMEM() __builtin_amdgcn_sched_barrier(0x38F)

// counted-wait barrier: drain LDS ops + all but the newest 4 vmem ops (the
// x-prefetch stays in flight across the barrier; B gload_lds guaranteed
// landed because they are provably older in the FIFO).
__device__ __forceinline__ void pipe_barrier() {
  asm volatile("s_waitcnt lgkmcnt(0)" ::: "memory");
  asm volatile("s_waitcnt vmcnt(4)" ::: "memory");
  __builtin_amdgcn_s_barrier();
  asm volatile("" ::: "memory");
}

// ---------------------------------------------------------------------------
// W [2048][512] f32 -> WT [512][2048] bf16, gamma folded in.
// ---------------------------------------------------------------------------
__global__ __launch_bounds__(256) void wt_kernel(const float* __restrict__ W,
                                                 const float* __restrict__ gamma,
                                                 unsigned short* __restrict__ WT) {
  __shared__ float tile[64][68];
  const int t  = threadIdx.x;
  const int bk = blockIdx.x >> 3;
  const int bn = blockIdx.x & 7;
  const int c4 = (t & 15) * 4;
#pragma unroll
  for (int i = 0; i < 4; ++i) {
    const int r = (t >> 4) + i * 16;
    const f32x4 v = *(const f32x4*)&W[(size_t)(bk * 64 + r) * NDIM + bn * 64 + c4];
    tile[r][c4 + 0] = v.x; tile[r][c4 + 1] = v.y;
    tile[r][c4 + 2] = v.z; tile[r][c4 + 3] = v.w;
  }
  __syncthreads();
#pragma unroll
  for (int j = 0; j < 2; ++j) {
    const int n  = j * 32 + (t >> 3);
    const int kb = (t & 7) * 8;
    const int kg0 = (bk & 7) * 64 + kb;
    const f32x4 g0 = *(const f32x4*)(gamma + kg0);
    const f32x4 g1 = *(const f32x4*)(gamma + kg0 + 4);
    const float gg[8] = {g0.x, g0.y, g0.z, g0.w, g1.x, g1.y, g1.z, g1.w};
    u16x8 o;
#pragma unroll
    for (int q = 0; q < 8; ++q) o[q] = f2bf(gg[q] * tile[kb + q][n]);
    *(u16x8*)&WT[(size_t)(bn * 64 + n) * KDIM + bk * 64 + kb] = o;
  }
}

// ---------------------------------------------------------------------------
// beta fold: partial[32][512] then reduce + b.
// ---------------------------------------------------------------------------
__global__ __launch_bounds__(256) void kbias1(const float* __restrict__ W,
                                              const float* __restrict__ beta,
                                              float* __restrict__ partial) {
  const int bk = blockIdx.x, tid = threadIdx.x;
  float a0 = 0.f, a1 = 0.f;
  for (int k = 0; k < 64; ++k) {
    const int kg = bk * 64 + k;
    const float be = beta[kg & (E - 1)];
    a0 += be * W[(size_t)kg * NDIM + tid];
    a1 += be * W[(size_t)kg * NDIM + 256 + tid];
  }
  partial[bk * NDIM + tid] = a0;
  partial[bk * NDIM + 256 + tid] = a1;
}

__global__ __launch_bounds__(256) void kbias2(const float* __restrict__ b,
                                              const float* __restrict__ partial,
                                              float* __restrict__ biasf) {
  const int c = blockIdx.x * 256 + threadIdx.x;
  float s = b[c];
  for (int j = 0; j < 32; ++j) s += partial[j * NDIM + c];
  biasf[c] = s;
}

// ---------------------------------------------------------------------------
// Stats: one wave per x-row of 512 -> (rs, nm) = (rstd, -mean*rstd)
// ---------------------------------------------------------------------------
__global__ __launch_bounds__(256, 4) void stats_kernel(const float* __restrict__ x,
                                                       f32x2* __restrict__ stats) {
  const int w = threadIdx.x >> 6, l = threadIdx.x & 63;
  const size_t row = (size_t)blockIdx.x * 4 + w;
  const float* xr = x + row * E + l * 8;
  const f32x4 v0 = *(const f32x4*)xr;
  const f32x4 v1 = *(const f32x4*)(xr + 4);
  float s = v0.x + v0.y + v0.z + v0.w + v1.x + v1.y + v1.z + v1.w;
  float q = v0.x * v0.x + v0.y * v0.y + v0.z * v0.z + v0.w * v0.w
          + v1.x * v1.x + v1.y * v1.y + v1.z * v1.z + v1.w * v1.w;
#pragma unroll
  for (int off = 32; off > 0; off >>= 1) {
    s += __shfl_xor(s, off);
    q += __shfl_xor(q, off);
  }
  if (l == 0) {
    const float mean = s * (1.0f / E);
    const float var  = q * (1.0f / E) - mean * mean;
    const float rs   = rsqrtf(var + 1e-6f);
    f32x2 o; o.x = rs; o.y = -mean * rs;
    stats[row] = o;
  }
}

// ---------------------------------------------------------------------------
// Fused norm+GEMM, counted-wait pipeline (T4), order-pinned.
// Tile 64x256, BK=64, 4 waves (wave = 64 rows x 64 cols).
// A: x f32 -> reg (2-deep dbuf) -> LN fma -> bf16 -> swizzled ds_write.
//    All 8 stats pairs preloaded in prologue (loadx = exactly 4 vmem ops).
// B: WT via coalesced gload_lds (pre-swizzled source, linear dest), 1 ahead.
// FIFO at pipe_barrier is provably [B(t+1) x8][x(t+2) x4] (SB_NOVMEM pins
// order) -> vmcnt(4) = B landed, x stays in flight across the barrier.
// LDS 2x40960 = 80KB -> 2 blocks/CU. Grid 512, XCD-chunked.
// ---------------------------------------------------------------------------
__global__ __launch_bounds__(256, 2) void gemm_kernel(const float* __restrict__ x,
                                                      const f32x2* __restrict__ stats,
                                                      const unsigned short* __restrict__ Bt,
                                                      const float* __restrict__ biasf,
                                                      float* __restrict__ out) {
  __shared__ char smem[2 * 40960];   // per buf: A 8KB @0, B 32KB @8192
  const int tid = threadIdx.x;
  const int l = tid & 63, w = tid >> 6;
  const int l7 = l & 7, l15 = l & 15, lhi = l >> 4;

  const int wg = ((blockIdx.x & 7) << 6) | (blockIdx.x >> 3);  // XCD chunking
  const int bn = wg & 1;
  const int bm = wg >> 1;
  const size_t mrow0 = (size_t)bm * 64;
  const int    ncol0 = bn * 256;

  // A staging: thread covers rows {amrow, amrow+32}, f32 cols (tid&7)*8..+8
  const int amrow = tid >> 3;
  const float* gx = x + (mrow0 + amrow) * KDIM + (tid & 7) * 8;
  const int sbase = (int)(mrow0 + amrow) * 4;
  const int awz   = ((tid & 7) * 16) ^ ((amrow & 7) << 4);

  // B staging: 8 gload16/thread, rows i*32 + w*8 + l/8, pre-swizzled source
  const int bsrow = w * 8 + (l >> 3);
  const int bswz  = (l7 * 16) ^ ((l >> 3) << 4);
  const char* gB = (const char*)Bt + ((size_t)(ncol0 + bsrow) * KDIM) * 2 + bswz;

  f32x4 acc[4][4];
#pragma unroll
  for (int m = 0; m < 4; ++m)
#pragma unroll
    for (int n = 0; n < 4; ++n) acc[m][n] = (f32x4){0.f, 0.f, 0.f, 0.f};

  const int cs0 = (lhi * 16) ^ (l7 * 16);

  f32x4 xa0[4], xa1[4];

  // ---- stats preload: the only 8 pairs this thread ever needs ----
  const f32x2 sa0 = stats[sbase + 0], sa1 = stats[sbase + 1];
  const f32x2 sa2 = stats[sbase + 2], sa3 = stats[sbase + 3];
  const f32x2 sb0 = stats[sbase + 128], sb1 = stats[sbase + 129];
  const f32x2 sb2 = stats[sbase + 130], sb3 = stats[sbase + 131];

  auto loadx = [&](f32x4* XA, int t) {   // exactly 4 vmem ops
    const float* p = gx + (size_t)t * 64;
    XA[0] = *(const f32x4*)(p);
    XA[1] = *(const f32x4*)(p + 4);
    XA[2] = *(const f32x4*)(p + (size_t)32 * KDIM);
    XA[3] = *(const f32x4*)(p + (size_t)32 * KDIM + 4);
  };
  auto writeA = [&](const f32x4* XA, int t) {
    const int tok = t >> 3;              // wave-uniform -> cheap selects
    const f32x2 s0 = tok == 0 ? sa0 : tok == 1 ? sa1 : tok == 2 ? sa2 : sa3;
    const f32x2 s1 = tok == 0 ? sb0 : tok == 1 ? sb1 : tok == 2 ? sb2 : sb3;
    char* ab = smem + (t & 1) * 40960;
    bf16x8 o;
    float rs = s0.x, nm = s0.y;
    o[0] = (__bf16)(XA[0].x * rs + nm); o[1] = (__bf16)(XA[0].y * rs + nm);
    o[2] = (__bf16)(XA[0].z * rs + nm); o[3] = (__bf16)(XA[0].w * rs + nm);
    o[4] = (__bf16)(XA[1].x * rs + nm); o[5] = (__bf16)(XA[1].y * rs + nm);
    o[6] = (__bf16)(XA[1].z * rs + nm); o[7] = (__bf16)(XA[1].w * rs + nm);
    *(bf16x8*)(ab + amrow * 128 + awz) = o;
    rs = s1.x; nm = s1.y;
    o[0] = (__bf16)(XA[2].x * rs + nm); o[1] = (__bf16)(XA[2].y * rs + nm);
    o[2] = (__bf16)(XA[2].z * rs + nm); o[3] = (__bf16)(XA[2].w * rs + nm);
    o[4] = (__bf16)(XA[3].x * rs + nm); o[5] = (__bf16)(XA[3].y * rs + nm);
    o[6] = (__bf16)(XA[3].z * rs + nm); o[7] = (__bf16)(XA[3].w * rs + nm);
    *(bf16x8*)(ab + (amrow + 32) * 128 + awz) = o;
  };
  auto stageB = [&](int t) {   // exactly 8 vmem ops
    char* bb = smem + (t & 1) * 40960 + 8192;
    const char* pb = gB + (size_t)t * 128;
#pragma unroll
    for (int i = 0; i < 8; ++i)
      gload16(pb + (size_t)i * 32 * KDIM * 2, bb + (i * 32 + w * 8) * 128);
  };
  auto mm = [&](int t) {
    const char* Ab = smem + (t & 1) * 40960;
    const char* Bb = Ab + 8192;
#pragma unroll
    for (int kk = 0; kk < 2; ++kk) {
      const int co = cs0 ^ (kk * 64);
      bf16x8 av[4], bv[4];
#pragma unroll
      for (int m = 0; m < 4; ++m)
        av[m] = *(const bf16x8*)(Ab + (m * 16 + l15) * 128 + co);
#pragma unroll
      for (int n = 0; n < 4; ++n)
        bv[n] = *(const bf16x8*)(Bb + (w * 64 + n * 16 + l15) * 128 + co);
#pragma unroll
      for (int m = 0; m < 4; ++m)
#pragma unroll
        for (int n = 0; n < 4; ++n)
          acc[m][n] = __builtin_amdgcn_mfma_f32_16x16x32_bf16(av[m], bv[n],
                                                              acc[m][n], 0, 0, 0);
    }
  };

  // prologue — FIFO (pinned): [stats(8), x0(4)] ... B0(8) ... x1(4).
  // writeA(0) makes the compiler drain stats+x0; vmcnt(4) then leaves x1 only.
  loadx(xa0, 0);
  SB_NOVMEM();
  stageB(0);
  SB_NOVMEM();
  loadx(xa1, 1);
  writeA(xa0, 0);
  pipe_barrier();

  for (int t = 0; t < NT; t += 2) {
    // even: FIFO adds B(t+1)[8] then x(t+2)[4] (dummy keeps tail uniform)
    stageB(t + 1);
    SB_NOVMEM();
    loadx(xa0, (t + 2 < NT) ? t + 2 : 0);
    SB_NOVMEM();
    mm(t);
    writeA(xa1, t + 1);
    pipe_barrier();
    // odd
    if (t + 2 < NT) {
      stageB(t + 2);
      SB_NOVMEM();
      loadx(xa1, (t + 3 < NT) ? t + 3 : 0);
      SB_NOVMEM();
      mm(t + 1);
      writeA(xa0, t + 2);
      pipe_barrier();
    } else {
      mm(t + 1);   // final K-step: B/A staged last even step, barrier passed
    }
  }

  // epilogue: bias + fast gelu. C/D layout: col = l&15, row = (l>>4)*4 + reg
#pragma unroll
  for (int n = 0; n < 4; ++n) {
    const int col = ncol0 + w * 64 + n * 16 + l15;
    const float bb = biasf[col];
#pragma unroll
    for (int m = 0; m < 4; ++m) {
      const size_t rbase = mrow0 + m * 16 + lhi * 4;
#pragma unroll
      for (int r = 0; r < 4; ++r) {
        const float v = acc[m][n][r] + bb;
        out[(rbase + r) * NDIM + col] = gelu_f(v);
      }
    }
  }
}

// ---------------------------------------------------------------------------
extern "C" void kernel_launch(void* const* d_in, const int* in_sizes, int n_in,
                              void* d_out, int out_size, void* d_ws, size_t ws_size,
                              hipStream_t stream) {
  const float* x     = (const float*)d_in[0];
  const float* gamma = (const float*)d_in[1];
  const float* beta  = (const float*)d_in[2];
  const float* W     = (const float*)d_in[3];
  const float* b     = (const float*)d_in[4];
  float* out = (float*)d_out;

  // ws layout: WT 2MB | stats 512KB | partial 64KB | biasf 2KB
  char* p = (char*)d_ws;
  unsigned short* WT = (unsigned short*)p;            p += (size_t)NDIM * KDIM * 2;
  f32x2* stats       = (f32x2*)p;                     p += (size_t)XROWS * 8;
  float* partial     = (float*)p;                     p += (size_t)32 * NDIM * 4;
  float* biasf       = (float*)p;

  wt_kernel<<<256, 256, 0, stream>>>(W, gamma, WT);
  kbias1<<<32, 256, 0, stream>>>(W, beta, partial);
  kbias2<<<2, 256, 0, stream>>>(b, partial, biasf);
  stats_kernel<<<XROWS / 4, 256, 0, stream>>>(x, stats);
  gemm_kernel<<<(MROWS / 64) * 2, 256, 0, stream>>>(x, stats, WT, biasf, out);
}

// Round 7
// 83.691 us; speedup vs baseline: 2.1748x; 1.1688x over previous
//
#include <hip/hip_runtime.h>
#include <hip/hip_bf16.h>
#include <cstdint>

// x: [8,8192,512] f32 -> LN over E=512 -> h=[16384,2048] bf16 (row-major flatten)
// W: [2048,512] f32, b: [512]; out = gelu(h @ W' + b'),
// W' = gamma-folded W (bf16, transposed), b' = b + beta @ W.
#define XROWS   65536
#define E       512
#define MROWS   16384
#define KDIM    2048
#define NDIM    512
#define NT      32        // K-steps of 64

typedef __attribute__((ext_vector_type(4))) float f32x4;
typedef __attribute__((ext_vector_type(8))) unsigned short u16x8;
typedef __attribute__((ext_vector_type(8))) __bf16 bf16x8;

__device__ __forceinline__ unsigned short f2bf(float f) {
  unsigned u = __builtin_bit_cast(unsigned, f);
  u += 0x7FFFu + ((u >> 16) & 1u);   // round-to-nearest-even
  return (unsigned short)(u >> 16);
}

typedef const __attribute__((address_space(1))) unsigned char ga_u8;
typedef __attribute__((address_space(3))) unsigned char ls_u8;
__device__ __forceinline__ void gload16(const void* g, void* l) {
  __builtin_amdgcn_global_load_lds((ga_u8*)g, (ls_u8*)l, 16, 0, 0);
}

// fast gelu (tanh form), |err vs erf form| <= ~3e-3 << 0.094 threshold
__device__ __forceinline__ float gelu_f(float v) {
  float p = v * (2.3022083f + 0.1029432f * (v * v));
  p = fminf(p, 80.0f);
  const float Ee = exp2f(p);
  return v * Ee * __builtin_amdgcn_rcpf(Ee + 1.0f);
}

// ---------------------------------------------------------------------------
// W [2048][512] f32 -> WT [512][2048] bf16, gamma folded in:
//   WT[n][k] = bf16(gamma[k % 512] * W[k][n])
// ---------------------------------------------------------------------------
__global__ __launch_bounds__(256) void wt_kernel(const float* __restrict__ W,
                                                 const float* __restrict__ gamma,
                                                 unsigned short* __restrict__ WT) {
  __shared__ float tile[64][68];
  const int t  = threadIdx.x;
  const int bk = blockIdx.x >> 3;
  const int bn = blockIdx.x & 7;
  const int c4 = (t & 15) * 4;
#pragma unroll
  for (int i = 0; i < 4; ++i) {
    const int r = (t >> 4) + i * 16;
    const f32x4 v = *(const f32x4*)&W[(size_t)(bk * 64 + r) * NDIM + bn * 64 + c4];
    tile[r][c4 + 0] = v.x; tile[r][c4 + 1] = v.y;
    tile[r][c4 + 2] = v.z; tile[r][c4 + 3] = v.w;
  }
  __syncthreads();
#pragma unroll
  for (int j = 0; j < 2; ++j) {
    const int n  = j * 32 + (t >> 3);
    const int kb = (t & 7) * 8;
    const int kg0 = (bk & 7) * 64 + kb;
    const f32x4 g0 = *(const f32x4*)(gamma + kg0);
    const f32x4 g1 = *(const f32x4*)(gamma + kg0 + 4);
    const float gg[8] = {g0.x, g0.y, g0.z, g0.w, g1.x, g1.y, g1.z, g1.w};
    u16x8 o;
#pragma unroll
    for (int q = 0; q < 8; ++q) o[q] = f2bf(gg[q] * tile[kb + q][n]);
    *(u16x8*)&WT[(size_t)(bn * 64 + n) * KDIM + bk * 64 + kb] = o;
  }
}

// ---------------------------------------------------------------------------
// beta fold: partial[32][512] then reduce + b.
// ---------------------------------------------------------------------------
__global__ __launch_bounds__(256) void kbias1(const float* __restrict__ W,
                                              const float* __restrict__ beta,
                                              float* __restrict__ partial) {
  const int bk = blockIdx.x, tid = threadIdx.x;
  float a0 = 0.f, a1 = 0.f;
  for (int k = 0; k < 64; ++k) {
    const int kg = bk * 64 + k;
    const float be = beta[kg & (E - 1)];
    a0 += be * W[(size_t)kg * NDIM + tid];
    a1 += be * W[(size_t)kg * NDIM + 256 + tid];
  }
  partial[bk * NDIM + tid] = a0;
  partial[bk * NDIM + 256 + tid] = a1;
}

__global__ __launch_bounds__(256) void kbias2(const float* __restrict__ b,
                                              const float* __restrict__ partial,
                                              float* __restrict__ biasf) {
  const int c = blockIdx.x * 256 + threadIdx.x;
  float s = b[c];
  for (int j = 0; j < 32; ++j) s += partial[j * NDIM + c];
  biasf[c] = s;
}

// ---------------------------------------------------------------------------
// LayerNorm: one wave per x-row of 512 f32 -> bf16 h (proven R1 kernel;
// gamma/beta are folded into WT/biasf, so plain (x-mean)*rstd here).
// ---------------------------------------------------------------------------
__global__ __launch_bounds__(256, 4) void ln_kernel(const float* __restrict__ x,
                                                    unsigned short* __restrict__ h) {
  const int w = threadIdx.x >> 6, l = threadIdx.x & 63;
  const size_t row = (size_t)blockIdx.x * 4 + w;
  const float* xr = x + row * E + l * 8;
  const f32x4 v0 = *(const f32x4*)xr;
  const f32x4 v1 = *(const f32x4*)(xr + 4);
  float xv[8] = {v0.x, v0.y, v0.z, v0.w, v1.x, v1.y, v1.z, v1.w};
  float s = 0.f, q = 0.f;
#pragma unroll
  for (int j = 0; j < 8; ++j) { s += xv[j]; q += xv[j] * xv[j]; }
#pragma unroll
  for (int off = 32; off > 0; off >>= 1) {
    s += __shfl_xor(s, off);
    q += __shfl_xor(q, off);
  }
  const float mean = s * (1.0f / E);
  const float var  = q * (1.0f / E) - mean * mean;
  const float rstd = rsqrtf(var + 1e-6f);
  const float nm   = -mean * rstd;
  u16x8 o;
#pragma unroll
  for (int j = 0; j < 8; ++j) o[j] = f2bf(xv[j] * rstd + nm);
  *(u16x8*)(h + row * E + l * 8) = o;
}

// ---------------------------------------------------------------------------
// GEMM: h[16384 x 2048 bf16] x WT[512 x 2048 bf16] -> out f32, + bias+gelu.
// m97-faithful: 128x128 tile, BK=64, SINGLE 32KB buffer, 2 barriers/K-step,
// gload_lds staging (linear dest + pre-swizzled source; T2 XOR on ds_read),
// __launch_bounds__(256,3) -> 3 blocks/CU (12 waves/CU).
// T1: XCD-chunked bijective swizzle (512 = 8*64): all 4 bn-siblings of a bm
// land on one XCD -> h-panel fetched from HBM once, L2-hit for the rest.
// ---------------------------------------------------------------------------
__global__ __launch_bounds__(256, 3) void gemm_kernel(const unsigned short* __restrict__ A,
                                                      const unsigned short* __restrict__ Bt,
                                                      const float* __restrict__ biasf,
                                                      float* __restrict__ out) {
  __shared__ char smem[32768];   // A 16KB @0, B 16KB @16384
  const int tid = threadIdx.x;
  const int l = tid & 63, w = tid >> 6;
  const int l7 = l & 7, l15 = l & 15, lhi = l >> 4;
  const int wr = w >> 1, wc = w & 1;

  // XCD chunking: grid 512 = 8 XCDs x 64; bn in low 2 bits of wg
  const int wg = ((blockIdx.x & 7) << 6) | (blockIdx.x >> 3);
  const int bn = wg & 3;
  const int bm = wg >> 2;
  const size_t arow0 = (size_t)bm * 128;
  const int    brow0 = bn * 128;

  // staging: thread covers rows {i*32 + w*8 + (l>>3)}, swizzled source col
  const int srow = w * 8 + (l >> 3);
  const int swz  = (l7 * 16) ^ ((l >> 3) << 4);
  const char* gA = (const char*)A  + ((size_t)(arow0 + srow) * KDIM) * 2 + swz;
  const char* gB = (const char*)Bt + ((size_t)(brow0 + srow) * KDIM) * 2 + swz;

  f32x4 acc[4][4];
#pragma unroll
  for (int m = 0; m < 4; ++m)
#pragma unroll
    for (int n = 0; n < 4; ++n) acc[m][n] = (f32x4){0.f, 0.f, 0.f, 0.f};

  // frag-read swizzled k-byte for kk=0; kk=1 flips bit 6 (outside swizzle)
  const int cs0 = (lhi * 16) ^ (l7 * 16);

  for (int t = 0; t < NT; ++t) {
    __syncthreads();               // all waves done reading buffer
    {
      const char* pa = gA + (size_t)t * 128;
      const char* pb = gB + (size_t)t * 128;
#pragma unroll
      for (int i = 0; i < 4; ++i) {
        gload16(pa + (size_t)i * 32 * KDIM * 2, smem + (i * 32 + w * 8) * 128);
        gload16(pb + (size_t)i * 32 * KDIM * 2, smem + 16384 + (i * 32 + w * 8) * 128);
      }
    }
    __syncthreads();               // drains vmcnt(0): staged data visible
#pragma unroll
    for (int kk = 0; kk < 2; ++kk) {
      const int co = cs0 ^ (kk * 64);
      bf16x8 av[4], bv[4];
#pragma unroll
      for (int m = 0; m < 4; ++m)
        av[m] = *(const bf16x8*)(smem + (wr * 64 + m * 16 + l15) * 128 + co);
#pragma unroll
      for (int n = 0; n < 4; ++n)
        bv[n] = *(const bf16x8*)(smem + 16384 + (wc * 64 + n * 16 + l15) * 128 + co);
#pragma unroll
      for (int m = 0; m < 4; ++m)
#pragma unroll
        for (int n = 0; n < 4; ++n)
          acc[m][n] = __builtin_amdgcn_mfma_f32_16x16x32_bf16(av[m], bv[n],
                                                              acc[m][n], 0, 0, 0);
    }
  }

  // epilogue: bias + fast gelu. C/D layout (m89): col = l&15, row = (l>>4)*4+reg
#pragma unroll
  for (int n = 0; n < 4; ++n) {
    const int col = brow0 + wc * 64 + n * 16 + l15;
    const float bb = biasf[col];
#pragma unroll
    for (int m = 0; m < 4; ++m) {
      const size_t rbase = arow0 + wr * 64 + m * 16 + lhi * 4;
#pragma unroll
      for (int r = 0; r < 4; ++r) {
        const float v = acc[m][n][r] + bb;
        out[(rbase + r) * NDIM + col] = gelu_f(v);
      }
    }
  }
}

// ---------------------------------------------------------------------------
extern "C" void kernel_launch(void* const* d_in, const int* in_sizes, int n_in,
                              void* d_out, int out_size, void* d_ws, size_t ws_size,
                              hipStream_t stream) {
  const float* x     = (const float*)d_in[0];
  const float* gamma = (const float*)d_in[1];
  const float* beta  = (const float*)d_in[2];
  const float* W     = (const float*)d_in[3];
  const float* b     = (const float*)d_in[4];
  float* out = (float*)d_out;

  // ws layout: WT 2MB | h 64MB | partial 64KB | biasf 2KB
  char* p = (char*)d_ws;
  unsigned short* WT = (unsigned short*)p;            p += (size_t)NDIM * KDIM * 2;
  unsigned short* h  = (unsigned short*)p;            p += (size_t)MROWS * KDIM * 2;
  float* partial     = (float*)p;                     p += (size_t)32 * NDIM * 4;
  float* biasf       = (float*)p;

  wt_kernel<<<256, 256, 0, stream>>>(W, gamma, WT);
  kbias1<<<32, 256, 0, stream>>>(W, beta, partial);
  kbias2<<<2, 256, 0, stream>>>(b, partial, biasf);
  ln_kernel<<<XROWS / 4, 256, 0, stream>>>(x, h);
  gemm_kernel<<<(MROWS / 128) * 4, 256, 0, stream>>>(h, WT, biasf, out);
}